// Round 2
// baseline (1379.070 us; speedup 1.0000x reference)
//
#include <hip/hip_runtime.h>
#include <hip/hip_bf16.h>
#include <stdint.h>

#define S0N 663552
#define S1N 73728
#define S2N 8192

typedef __attribute__((ext_vector_type(8))) short bf16x8;
typedef __attribute__((ext_vector_type(4))) float floatx4;

__device__ __forceinline__ unsigned short f2b(float f) {
    union { float f; unsigned u; } v; v.f = f;
    unsigned r = v.u + 0x7fffu + ((v.u >> 16) & 1u);   // RNE to bf16
    return (unsigned short)(r >> 16);
}
__device__ __forceinline__ float b2f(unsigned short h) {
    union { unsigned u; float f; } v; v.u = ((unsigned)h) << 16;
    return v.f;
}
__device__ __forceinline__ bf16x8 pack8(float4 a, float4 b) {
    bf16x8 r;
    r[0] = (short)f2b(a.x); r[1] = (short)f2b(a.y);
    r[2] = (short)f2b(a.z); r[3] = (short)f2b(a.w);
    r[4] = (short)f2b(b.x); r[5] = (short)f2b(b.y);
    r[6] = (short)f2b(b.z); r[7] = (short)f2b(b.w);
    return r;
}

// ---------------------------------------------------------------------------
// k_h0: h0[i] = node_emb[parent0[i]+1] + leaky(content0[i] @ Wp^T + bp), bf16
// B (Wp) staged to LDS once; A (content) loaded direct global->reg (no reuse).
// K-loop has ZERO barriers. Epilogue transposes through LDS for vector I/O.
// ---------------------------------------------------------------------------
__global__ __launch_bounds__(256, 2) void k_h0(
    const float* __restrict__ content, const float* __restrict__ Wp,
    const float* __restrict__ bp, const float* __restrict__ node_emb,
    const int* __restrict__ parent0, unsigned short* __restrict__ h0)
{
    __shared__ unsigned short Bs[128 * 264];   // Wp as bf16, rows padded to 264
    const int tid = threadIdx.x;
    const int wave = tid >> 6, lane = tid & 63;
    const int l15 = lane & 15, quad = lane >> 4;
    const int row0 = blockIdx.x * 128;

    // stage Wp (128x256 fp32 -> bf16), 128 elems/thread as 8B packed writes
    {
        const int r = tid >> 1, cb = (tid & 1) * 128;
        const float* src = Wp + r * 256 + cb;
        unsigned short* dst = &Bs[r * 264 + cb];
        #pragma unroll
        for (int i = 0; i < 32; ++i) {
            const float4 v = ((const float4*)src)[i];
            ushort4 o; o.x = f2b(v.x); o.y = f2b(v.y); o.z = f2b(v.z); o.w = f2b(v.w);
            ((ushort4*)dst)[i] = o;
        }
    }
    __syncthreads();

    floatx4 acc[2][8];
    #pragma unroll
    for (int i = 0; i < 2; ++i)
        #pragma unroll
        for (int j = 0; j < 8; ++j) acc[i][j] = (floatx4)0.f;

    const int arow = row0 + wave * 32;
    #pragma unroll
    for (int kc = 0; kc < 8; ++kc) {           // 8 chunks of K=32, no barriers
        bf16x8 a[2];
        #pragma unroll
        for (int mt = 0; mt < 2; ++mt) {
            const float* ap = content + (size_t)(arow + mt * 16 + l15) * 256 + kc * 32 + quad * 8;
            a[mt] = pack8(((const float4*)ap)[0], ((const float4*)ap)[1]);
        }
        #pragma unroll
        for (int nt = 0; nt < 8; ++nt) {
            const bf16x8 b = *(const bf16x8*)&Bs[(nt * 16 + l15) * 264 + kc * 32 + quad * 8];
            #pragma unroll
            for (int mt = 0; mt < 2; ++mt)
                acc[mt][nt] = __builtin_amdgcn_mfma_f32_16x16x32_bf16(a[mt], b, acc[mt][nt], 0, 0, 0);
        }
    }

    // epilogue: bias+leaky into fp32 LDS (C-layout scatter), then vectorized
    // row pass: +node_emb (float4 gather) -> bf16 -> uint4 stores
    __syncthreads();                            // done with Bs as Wp
    float* T = (float*)Bs;                      // [128][132] fp32, 67.6KB fits
    float bpv[8];
    #pragma unroll
    for (int nt = 0; nt < 8; ++nt) bpv[nt] = bp[nt * 16 + l15];
    #pragma unroll
    for (int mt = 0; mt < 2; ++mt)
        #pragma unroll
        for (int r = 0; r < 4; ++r) {
            const int lrow = wave * 32 + mt * 16 + quad * 4 + r;
            #pragma unroll
            for (int nt = 0; nt < 8; ++nt) {
                float v = acc[mt][nt][r] + bpv[nt];
                v = v > 0.f ? v : 0.1f * v;
                T[lrow * 132 + nt * 16 + l15] = v;
            }
        }
    __syncthreads();
    {
        const int r = tid >> 1, cb = (tid & 1) * 64;
        const int grow = row0 + r;
        const float* ne = node_emb + (size_t)(parent0[grow] + 1) * 128 + cb;
        unsigned short* orow = h0 + (size_t)grow * 128 + cb;
        #pragma unroll
        for (int i = 0; i < 8; ++i) {
            const float4 t0 = *(const float4*)&T[r * 132 + cb + i * 8];
            const float4 t1 = *(const float4*)&T[r * 132 + cb + i * 8 + 4];
            const float4 n0 = ((const float4*)ne)[2 * i];
            const float4 n1 = ((const float4*)ne)[2 * i + 1];
            union { ushort u[8]; uint4 q; } o;
            o.u[0] = f2b(t0.x + n0.x); o.u[1] = f2b(t0.y + n0.y);
            o.u[2] = f2b(t0.z + n0.z); o.u[3] = f2b(t0.w + n0.w);
            o.u[4] = f2b(t1.x + n1.x); o.u[5] = f2b(t1.y + n1.y);
            o.u[6] = f2b(t1.z + n1.z); o.u[7] = f2b(t1.w + n1.w);
            *(uint4*)(orow + i * 8) = o.q;
        }
    }
}

// ---------------------------------------------------------------------------
// k_gather: out[d] = (sum_{j<8} hsrc[src[randOff+d*8+j]] (+hself[d]-hsub[d]))/8
// one wave per dst row; lane handles a bf16 pair -> 256B coalesced row reads
// ---------------------------------------------------------------------------
__global__ __launch_bounds__(256, 4) void k_gather(
    const unsigned short* __restrict__ hsrc, const int* __restrict__ srcIdx,
    int randOff, const unsigned short* __restrict__ hself,
    const unsigned short* __restrict__ hsub, unsigned short* __restrict__ out)
{
    const int wave = threadIdx.x >> 6, lane = threadIdx.x & 63;
    const int d = blockIdx.x * 4 + wave;
    const int c2 = lane * 2;
    int idx[8];
    #pragma unroll
    for (int j = 0; j < 8; ++j) idx[j] = srcIdx[randOff + d * 8 + j];
    unsigned v[8];
    #pragma unroll
    for (int j = 0; j < 8; ++j)
        v[j] = *(const unsigned*)(hsrc + (size_t)idx[j] * 128 + c2);
    float ax = 0.f, ay = 0.f;
    #pragma unroll
    for (int j = 0; j < 8; ++j) {
        ax += b2f((unsigned short)(v[j] & 0xffffu));
        ay += b2f((unsigned short)(v[j] >> 16));
    }
    if (hself) {   // conv1: + h1[d] - h0[d]
        const unsigned s = *(const unsigned*)(hself + (size_t)d * 128 + c2);
        const unsigned u = *(const unsigned*)(hsub + (size_t)d * 128 + c2);
        ax += b2f((unsigned short)(s & 0xffffu)) - b2f((unsigned short)(u & 0xffffu));
        ay += b2f((unsigned short)(s >> 16))     - b2f((unsigned short)(u >> 16));
    }
    ax *= 0.125f; ay *= 0.125f;
    *(unsigned*)(out + (size_t)d * 128 + c2) =
        (unsigned)f2b(ax) | ((unsigned)f2b(ay) << 16);
}

// stage a 128x128 fp32 block -> bf16 LDS [128][136]
__device__ __forceinline__ void stageB128(const float* __restrict__ W, int ldw,
                                          unsigned short* lds, int tid) {
    const int r = tid >> 1, cb = (tid & 1) * 64;
    const float* src = W + r * ldw + cb;
    unsigned short* dst = lds + r * 136 + cb;
    #pragma unroll
    for (int i = 0; i < 16; ++i) {
        const float4 v = ((const float4*)src)[i];
        ushort4 o; o.x = f2b(v.x); o.y = f2b(v.y); o.z = f2b(v.z); o.w = f2b(v.w);
        ((ushort4*)dst)[i] = o;
    }
}

// ---------------------------------------------------------------------------
// k_combine: h = act(A1@W[:,:128]^T + A2@W[:,128:]^T + b) + act(A2@Wagg^T+bagg)
// A1/A2 loaded direct from global (bf16, no reuse); W halves + Wagg in LDS.
// !LAST: act=leaky, row-L2-normalize, bf16 out.  LAST: no act, fp32 out.
// ---------------------------------------------------------------------------
template<bool LAST>
__global__ __launch_bounds__(256, 2) void k_combine(
    const unsigned short* __restrict__ A1, const unsigned short* __restrict__ A2,
    const float* __restrict__ W, const float* __restrict__ b,
    const float* __restrict__ Wagg, const float* __restrict__ bagg,
    unsigned short* __restrict__ outB, float* __restrict__ outF)
{
    __shared__ unsigned short BsA[128 * 136];
    __shared__ unsigned short BsB[128 * 136];
    const int tid = threadIdx.x;
    const int wave = tid >> 6, lane = tid & 63;
    const int l15 = lane & 15, quad = lane >> 4;
    const int row0 = blockIdx.x * 128;
    const int arow = row0 + wave * 32;

    floatx4 acc1[2][8], acc2[2][8];
    #pragma unroll
    for (int i = 0; i < 2; ++i)
        #pragma unroll
        for (int j = 0; j < 8; ++j) { acc1[i][j] = (floatx4)0.f; acc2[i][j] = (floatx4)0.f; }

    stageB128(W, 256, BsA, tid);        // W[:, 0:128]
    stageB128(Wagg, 128, BsB, tid);
    __syncthreads();

    #pragma unroll
    for (int kc = 0; kc < 4; ++kc) {    // phase 1: A1 x W[:,0:128] -> acc1
        bf16x8 a[2];
        #pragma unroll
        for (int mt = 0; mt < 2; ++mt)
            a[mt] = *(const bf16x8*)(A1 + (size_t)(arow + mt * 16 + l15) * 128 + kc * 32 + quad * 8);
        #pragma unroll
        for (int nt = 0; nt < 8; ++nt) {
            const bf16x8 bb = *(const bf16x8*)&BsA[(nt * 16 + l15) * 136 + kc * 32 + quad * 8];
            #pragma unroll
            for (int mt = 0; mt < 2; ++mt)
                acc1[mt][nt] = __builtin_amdgcn_mfma_f32_16x16x32_bf16(a[mt], bb, acc1[mt][nt], 0, 0, 0);
        }
    }
    __syncthreads();
    stageB128(W + 128, 256, BsA, tid);  // W[:, 128:256]
    __syncthreads();
    #pragma unroll
    for (int kc = 0; kc < 4; ++kc) {    // phase 2: A2 x {Ws -> acc1, Wagg -> acc2}
        bf16x8 a[2];
        #pragma unroll
        for (int mt = 0; mt < 2; ++mt)
            a[mt] = *(const bf16x8*)(A2 + (size_t)(arow + mt * 16 + l15) * 128 + kc * 32 + quad * 8);
        #pragma unroll
        for (int nt = 0; nt < 8; ++nt) {
            const bf16x8 b1v = *(const bf16x8*)&BsA[(nt * 16 + l15) * 136 + kc * 32 + quad * 8];
            const bf16x8 b2v = *(const bf16x8*)&BsB[(nt * 16 + l15) * 136 + kc * 32 + quad * 8];
            #pragma unroll
            for (int mt = 0; mt < 2; ++mt) {
                acc1[mt][nt] = __builtin_amdgcn_mfma_f32_16x16x32_bf16(a[mt], b1v, acc1[mt][nt], 0, 0, 0);
                acc2[mt][nt] = __builtin_amdgcn_mfma_f32_16x16x32_bf16(a[mt], b2v, acc2[mt][nt], 0, 0, 0);
            }
        }
    }

    #pragma unroll
    for (int mt = 0; mt < 2; ++mt) {
        #pragma unroll
        for (int r = 0; r < 4; ++r) {
            const int grow = row0 + wave * 32 + mt * 16 + quad * 4 + r;
            float h[8]; float ssq = 0.f;
            #pragma unroll
            for (int nt = 0; nt < 8; ++nt) {
                const int col = nt * 16 + l15;
                float v1 = acc1[mt][nt][r] + b[col];
                float v2 = acc2[mt][nt][r] + bagg[col];
                if (!LAST) {
                    v1 = v1 > 0.f ? v1 : 0.1f * v1;
                    v2 = v2 > 0.f ? v2 : 0.1f * v2;
                }
                h[nt] = v1 + v2;
                ssq += h[nt] * h[nt];
            }
            if (LAST) {
                float* orow = outF + (size_t)grow * 128;
                #pragma unroll
                for (int nt = 0; nt < 8; ++nt) orow[nt * 16 + l15] = h[nt];
            } else {
                ssq += __shfl_xor(ssq, 1);
                ssq += __shfl_xor(ssq, 2);
                ssq += __shfl_xor(ssq, 4);
                ssq += __shfl_xor(ssq, 8);
                const float scale = 1.f / fmaxf(sqrtf(ssq), 1e-6f);
                unsigned short* orow = outB + (size_t)grow * 128;
                #pragma unroll
                for (int nt = 0; nt < 8; ++nt) orow[nt * 16 + l15] = f2b(h[nt] * scale);
            }
        }
    }
}

extern "C" void kernel_launch(void* const* d_in, const int* in_sizes, int n_in,
                              void* d_out, int out_size, void* d_ws, size_t ws_size,
                              hipStream_t stream)
{
    const float* node_emb = (const float*)d_in[0];
    const float* content0 = (const float*)d_in[1];
    const float* Wp    = (const float*)d_in[2];
    const float* bp    = (const float*)d_in[3];
    const float* W0    = (const float*)d_in[4];
    const float* b0    = (const float*)d_in[5];
    const float* Wagg0 = (const float*)d_in[6];
    const float* bagg0 = (const float*)d_in[7];
    const float* W1    = (const float*)d_in[8];
    const float* b1    = (const float*)d_in[9];
    const float* Wagg1 = (const float*)d_in[10];
    const float* bagg1 = (const float*)d_in[11];
    const int* parent0 = (const int*)d_in[12];
    const int* src0    = (const int*)d_in[13];
    const int* src1    = (const int*)d_in[15];

    unsigned short* h0    = (unsigned short*)d_ws;
    unsigned short* h1    = h0 + (size_t)S0N * 128;
    unsigned short* hagg0 = h1 + (size_t)S1N * 128;
    unsigned short* hagg1 = hagg0 + (size_t)S1N * 128;

    k_h0<<<S0N / 128, 256, 0, stream>>>(content0, Wp, bp, node_emb, parent0, h0);
    k_gather<<<S1N / 4, 256, 0, stream>>>(h0, src0, S1N, nullptr, nullptr, hagg0);
    k_combine<false><<<S1N / 128, 256, 0, stream>>>(h0, hagg0, W0, b0, Wagg0, bagg0, h1, nullptr);
    k_gather<<<S2N / 4, 256, 0, stream>>>(h1, src1, S2N, h1, h0, hagg1);
    k_combine<true><<<S2N / 128, 256, 0, stream>>>(h0, hagg1, W1, b1, Wagg1, bagg1, nullptr, (float*)d_out);
}